// Round 5
// baseline (1096.333 us; speedup 1.0000x reference)
//
#include <hip/hip_runtime.h>

#define B_ 4
#define H_ 256
#define W_ 256
#define Z_ 64
#define NB_ (H_*W_*Z_)      /* 4194304 */
#define N_  (B_*NB_)        /* 16777216 */
#define ITER_ 8
#define EPS_ 1e-6f
#define SLOTS_ 64

/* scal layout (floats) */
#define RHO_OFF   0
#define ETA_OFF   ((ITER_+1)*B_*SLOTS_)
#define LOSS_OFF  (ETA_OFF + ITER_*B_*SLOTS_)
#define MAXE_OFF  (LOSS_OFF + SLOTS_)
#define SCAL_FLOATS (MAXE_OFF + SLOTS_)

struct F8 { float4 a, b; };
typedef float v4f __attribute__((ext_vector_type(4)));

__device__ __forceinline__ float wsum(float v){
  v += __shfl_xor(v,32); v += __shfl_xor(v,16); v += __shfl_xor(v,8);
  v += __shfl_xor(v,4);  v += __shfl_xor(v,2);  v += __shfl_xor(v,1);
  return v;
}
__device__ __forceinline__ float wmaxr(float v){
  v = fmaxf(v,__shfl_xor(v,32)); v = fmaxf(v,__shfl_xor(v,16));
  v = fmaxf(v,__shfl_xor(v,8));  v = fmaxf(v,__shfl_xor(v,4));
  v = fmaxf(v,__shfl_xor(v,2));  v = fmaxf(v,__shfl_xor(v,1));
  return v;
}
__device__ __forceinline__ float read_sum(const float* s){
  return wsum(s[threadIdx.x & 63]);
}
__device__ __forceinline__ void block_atomic_sum(float v, float* dst, float* lds){
  v = wsum(v);
  int wid = threadIdx.x >> 6, lane = threadIdx.x & 63;
  if (lane == 0) lds[wid] = v;
  __syncthreads();
  if (threadIdx.x == 0) atomicAdd(dst, lds[0]+lds[1]+lds[2]+lds[3]);
}

__device__ __forceinline__ float4 ld4(const float* p){ return *(const float4*)p; }

__device__ __forceinline__ void sten_core(const F8& c, const F8& wm, const F8& wp,
                                          const F8& hm, const F8& hp,
                                          float zl, float zr, F8& st)
{
  st.a.x = 6.f*c.a.x - wm.a.x - wp.a.x - hm.a.x - hp.a.x - zl     - c.a.y;
  st.a.y = 6.f*c.a.y - wm.a.y - wp.a.y - hm.a.y - hp.a.y - c.a.x  - c.a.z;
  st.a.z = 6.f*c.a.z - wm.a.z - wp.a.z - hm.a.z - hp.a.z - c.a.y  - c.a.w;
  st.a.w = 6.f*c.a.w - wm.a.w - wp.a.w - hm.a.w - hp.a.w - c.a.z  - c.b.x;
  st.b.x = 6.f*c.b.x - wm.b.x - wp.b.x - hm.b.x - hp.b.x - c.a.w  - c.b.y;
  st.b.y = 6.f*c.b.y - wm.b.y - wp.b.y - hm.b.y - hp.b.y - c.b.x  - c.b.z;
  st.b.z = 6.f*c.b.z - wm.b.z - wp.b.z - hm.b.z - hp.b.z - c.b.y  - c.b.w;
  st.b.w = 6.f*c.b.w - wm.b.w - wp.b.w - hm.b.w - hp.b.w - c.b.z  - zr;
}

__device__ __forceinline__ void stencil1(const float* __restrict__ a, int base,
                                         int w, int h, int zc, F8& c, F8& st)
{
  c.a = ld4(a+base); c.b = ld4(a+base+4);
  F8 zero; zero.a = make_float4(0,0,0,0); zero.b = zero.a;
  F8 wm = zero, wp = zero, hm = zero, hp = zero;
  if (w > 0)    { wm.a = ld4(a+base-Z_);    wm.b = ld4(a+base-Z_+4); }
  if (w < W_-1) { wp.a = ld4(a+base+Z_);    wp.b = ld4(a+base+Z_+4); }
  if (h > 0)    { hm.a = ld4(a+base-W_*Z_); hm.b = ld4(a+base-W_*Z_+4); }
  if (h < H_-1) { hp.a = ld4(a+base+W_*Z_); hp.b = ld4(a+base+W_*Z_+4); }
  float zl = (zc > 0) ? a[base-1] : 0.f;
  float zr = (zc < 7) ? a[base+8] : 0.f;
  sten_core(c, wm, wp, hm, hp, zl, zr, st);
}

__device__ __forceinline__ F8 comb8(const float* r, const float* p, float beta, int idx){
  F8 o;
  float4 ra = ld4(r+idx), rb = ld4(r+idx+4);
  float4 pa = ld4(p+idx), pb = ld4(p+idx+4);
  o.a.x = ra.x + beta*pa.x; o.a.y = ra.y + beta*pa.y;
  o.a.z = ra.z + beta*pa.z; o.a.w = ra.w + beta*pa.w;
  o.b.x = rb.x + beta*pb.x; o.b.y = rb.y + beta*pb.y;
  o.b.z = rb.z + beta*pb.z; o.b.w = rb.w + beta*pb.w;
  return o;
}
__device__ __forceinline__ void stencil2(const float* __restrict__ r,
                                         const float* __restrict__ p, float beta,
                                         int base, int w, int h, int zc,
                                         F8& c, F8& st)
{
  c = comb8(r,p,beta,base);
  F8 zero; zero.a = make_float4(0,0,0,0); zero.b = zero.a;
  F8 wm = zero, wp = zero, hm = zero, hp = zero;
  if (w > 0)    wm = comb8(r,p,beta,base-Z_);
  if (w < W_-1) wp = comb8(r,p,beta,base+Z_);
  if (h > 0)    hm = comb8(r,p,beta,base-W_*Z_);
  if (h < H_-1) hp = comb8(r,p,beta,base+W_*Z_);
  float zl = (zc > 0) ? r[base-1] + beta*p[base-1] : 0.f;
  float zr = (zc < 7) ? r[base+8] + beta*p[base+8] : 0.f;
  sten_core(c, wm, wp, hm, hp, zl, zr, st);
}

#define IDX_SETUP \
  const int zc = threadIdx.x & 7; \
  const int wl = threadIdx.x >> 3; \
  const int w  = blockIdx.x*32 + wl; \
  const int h  = blockIdx.y; \
  const int bb = blockIdx.z; \
  const int base = ((bb*H_ + h)*W_ + w)*Z_ + zc*8; \
  const int flat = (blockIdx.z*gridDim.y + blockIdx.y)*gridDim.x + blockIdx.x; \
  const int slot = flat & (SLOTS_-1);

/* r = b - A x ; rho0 = <r,r> per batch */
__global__ __launch_bounds__(256) void k_init(const float* __restrict__ x,
                                              const float* __restrict__ b,
                                              float* __restrict__ r,
                                              float* scal)
{
  __shared__ float lds[4];
  IDX_SETUP
  F8 c, st;
  stencil1(x, base, w, h, zc, c, st);
  float4 b0 = ld4(b+base), b1 = ld4(b+base+4);
  F8 rv;
  rv.a = make_float4(b0.x-st.a.x, b0.y-st.a.y, b0.z-st.a.z, b0.w-st.a.w);
  rv.b = make_float4(b1.x-st.b.x, b1.y-st.b.y, b1.z-st.b.z, b1.w-st.b.w);
  *(float4*)(r+base)   = rv.a;
  *(float4*)(r+base+4) = rv.b;
  float rho = rv.a.x*rv.a.x + rv.a.y*rv.a.y + rv.a.z*rv.a.z + rv.a.w*rv.a.w
            + rv.b.x*rv.b.x + rv.b.y*rv.b.y + rv.b.z*rv.b.z + rv.b.w*rv.b.w;
  block_atomic_sum(rho, scal + RHO_OFF + (0*B_+bb)*SLOTS_ + slot, lds);
}

/* p0 = r ; eta0 = <r, A r> */
__global__ __launch_bounds__(256) void k_a0(const float* __restrict__ r,
                                            float* __restrict__ pnew,
                                            float* scal)
{
  __shared__ float lds[4];
  IDX_SETUP
  F8 c, st;
  stencil1(r, base, w, h, zc, c, st);
  *(float4*)(pnew+base)   = c.a;
  *(float4*)(pnew+base+4) = c.b;
  float eta = c.a.x*st.a.x + c.a.y*st.a.y + c.a.z*st.a.z + c.a.w*st.a.w
            + c.b.x*st.b.x + c.b.y*st.b.y + c.b.z*st.b.z + c.b.w*st.b.w;
  block_atomic_sum(eta, scal + ETA_OFF + (0*B_+bb)*SLOTS_ + slot, lds);
}

/* p_it = r + beta*p_{it-1} ; eta_it */
__global__ __launch_bounds__(256) void k_a(const float* __restrict__ r,
                                           const float* __restrict__ pold,
                                           float* __restrict__ pnew,
                                           float* scal, int it)
{
  __shared__ float lds[4];
  IDX_SETUP
  float num = read_sum(scal + RHO_OFF + (it*B_+bb)*SLOTS_);
  float den = read_sum(scal + RHO_OFF + ((it-1)*B_+bb)*SLOTS_);
  float beta = num / (den + EPS_);
  F8 c, st;
  stencil2(r, pold, beta, base, w, h, zc, c, st);
  *(float4*)(pnew+base)   = c.a;
  *(float4*)(pnew+base+4) = c.b;
  float eta = c.a.x*st.a.x + c.a.y*st.a.y + c.a.z*st.a.z + c.a.w*st.a.w
            + c.b.x*st.b.x + c.b.y*st.b.y + c.b.z*st.b.z + c.b.w*st.b.w;
  block_atomic_sum(eta, scal + ETA_OFF + (it*B_+bb)*SLOTS_ + slot, lds);
}

/* HISTORY path: r -= alpha*A p (no x traffic); rho_{it+1} */
__global__ __launch_bounds__(256) void k_bh(float* __restrict__ r,
                                            const float* __restrict__ p,
                                            float* scal, int it)
{
  __shared__ float lds[4];
  IDX_SETUP
  float num = read_sum(scal + RHO_OFF + (it*B_+bb)*SLOTS_);
  float den = read_sum(scal + ETA_OFF + (it*B_+bb)*SLOTS_);
  float alpha = num / (den + EPS_);
  F8 c, st;
  stencil1(p, base, w, h, zc, c, st);
  float4 r0 = ld4(r+base), r1 = ld4(r+base+4);
  r0.x -= alpha*st.a.x; r0.y -= alpha*st.a.y; r0.z -= alpha*st.a.z; r0.w -= alpha*st.a.w;
  r1.x -= alpha*st.b.x; r1.y -= alpha*st.b.y; r1.z -= alpha*st.b.z; r1.w -= alpha*st.b.w;
  *(float4*)(r+base)   = r0;
  *(float4*)(r+base+4) = r1;
  float rho = r0.x*r0.x + r0.y*r0.y + r0.z*r0.z + r0.w*r0.w
            + r1.x*r1.x + r1.y*r1.y + r1.z*r1.z + r1.w*r1.w;
  block_atomic_sum(rho, scal + RHO_OFF + ((it+1)*B_+bb)*SLOTS_ + slot, lds);
}

/* HISTORY path, last iteration: rho8 only, no r write */
__global__ __launch_bounds__(256) void k_bh_last(const float* __restrict__ r,
                                                 const float* __restrict__ p,
                                                 float* scal, int it)
{
  __shared__ float lds[4];
  IDX_SETUP
  float num = read_sum(scal + RHO_OFF + (it*B_+bb)*SLOTS_);
  float den = read_sum(scal + ETA_OFF + (it*B_+bb)*SLOTS_);
  float alpha = num / (den + EPS_);
  F8 c, st;
  stencil1(p, base, w, h, zc, c, st);
  float4 r0 = ld4(r+base), r1 = ld4(r+base+4);
  r0.x -= alpha*st.a.x; r0.y -= alpha*st.a.y; r0.z -= alpha*st.a.z; r0.w -= alpha*st.a.w;
  r1.x -= alpha*st.b.x; r1.y -= alpha*st.b.y; r1.z -= alpha*st.b.z; r1.w -= alpha*st.b.w;
  float rho = r0.x*r0.x + r0.y*r0.y + r0.z*r0.z + r0.w*r0.w
            + r1.x*r1.x + r1.y*r1.y + r1.z*r1.z + r1.w*r1.w;
  block_atomic_sum(rho, scal + RHO_OFF + ((it+1)*B_+bb)*SLOTS_ + slot, lds);
}

/* HISTORY path epilogue: out[1+i] = x0[i] + sum_j alpha_j p_j[i]; loss/maxerr.
   Aligned float4 stores via a 256-float boundary exchange (no bulk LDS). */
__global__ __launch_bounds__(256) void k_recon(const float* __restrict__ x0,
                                               const float* __restrict__ ref,
                                               const float* __restrict__ ph,
                                               float* __restrict__ out,
                                               float* scal)
{
  __shared__ float bnd[256];
  __shared__ float lds[8];
  IDX_SETUP
  (void)slot;
  float4 a0 = ld4(x0+base), a1 = ld4(x0+base+4);
  float v0=a0.x, v1=a0.y, v2=a0.z, v3=a0.w, v4=a1.x, v5=a1.y, v6=a1.z, v7=a1.w;
  #pragma unroll
  for (int j = 0; j < ITER_; ++j) {
    float num = read_sum(scal + RHO_OFF + (j*B_+bb)*SLOTS_);
    float den = read_sum(scal + ETA_OFF + (j*B_+bb)*SLOTS_);
    float alpha = num / (den + EPS_);
    const float* pj = ph + (size_t)j*N_;
    float4 q0 = ld4(pj+base), q1 = ld4(pj+base+4);
    v0 += alpha*q0.x; v1 += alpha*q0.y; v2 += alpha*q0.z; v3 += alpha*q0.w;
    v4 += alpha*q1.x; v5 += alpha*q1.y; v6 += alpha*q1.z; v7 += alpha*q1.w;
  }

  /* loss / maxerr vs reference */
  float4 f0 = ld4(ref+base), f1 = ld4(ref+base+4);
  float d0 = v0-f0.x, d1 = v1-f0.y, d2 = v2-f0.z, d3 = v3-f0.w;
  float d4 = v4-f1.x, d5 = v5-f1.y, d6 = v6-f1.z, d7 = v7-f1.w;
  float loss = d0*d0+d1*d1+d2*d2+d3*d3+d4*d4+d5*d5+d6*d6+d7*d7;
  float me = fmaxf(fmaxf(fmaxf(fabsf(d0),fabsf(d1)),fmaxf(fabsf(d2),fabsf(d3))),
                   fmaxf(fmaxf(fabsf(d4),fabsf(d5)),fmaxf(fabsf(d6),fabsf(d7))));
  float ls = wsum(loss), ms = wmaxr(me);
  const int t = threadIdx.x;
  int wid = t >> 6, lane = t & 63;
  if (lane == 0) { lds[wid] = ls; lds[4+wid] = ms; }

  /* boundary exchange: thread t needs thread (t-1)'s last element */
  bnd[t] = v7;
  __syncthreads();
  if (t == 0) {
    atomicAdd(scal + LOSS_OFF + (flat & (SLOTS_-1)), lds[0]+lds[1]+lds[2]+lds[3]);
    float bm = fmaxf(fmaxf(lds[4],lds[5]), fmaxf(lds[6],lds[7]));
    atomicMax((unsigned int*)(scal + MAXE_OFF) + (flat & (SLOTS_-1)), __float_as_uint(bm));
  }

  /* out flat span of this thread: out[S+8t+1 .. S+8t+8] (shift by +1) */
  const int S = flat * 2048;
  v4f chB = { v3, v4, v5, v6 };
  __builtin_nontemporal_store(chB, (v4f*)(out + S + 8*t + 4));
  if (t > 0) {
    v4f chA = { bnd[t-1], v0, v1, v2 };
    __builtin_nontemporal_store(chA, (v4f*)(out + S + 8*t));
  } else {
    out[S+1] = v0; out[S+2] = v1; out[S+3] = v2;
  }
  if (t == 255) out[S+2048] = v7;  /* first element of next block's span */
}

/* ------- fallback (round-3) kernels: x updated in-loop ------- */
__global__ __launch_bounds__(256) void k_b(float* __restrict__ x,
                                           float* __restrict__ r,
                                           const float* __restrict__ p,
                                           float* scal, int it)
{
  __shared__ float lds[4];
  IDX_SETUP
  float num = read_sum(scal + RHO_OFF + (it*B_+bb)*SLOTS_);
  float den = read_sum(scal + ETA_OFF + (it*B_+bb)*SLOTS_);
  float alpha = num / (den + EPS_);
  F8 c, st;
  stencil1(p, base, w, h, zc, c, st);
  float4 x0 = ld4(x+base), x1 = ld4(x+base+4);
  x0.x += alpha*c.a.x; x0.y += alpha*c.a.y; x0.z += alpha*c.a.z; x0.w += alpha*c.a.w;
  x1.x += alpha*c.b.x; x1.y += alpha*c.b.y; x1.z += alpha*c.b.z; x1.w += alpha*c.b.w;
  *(float4*)(x+base)   = x0;
  *(float4*)(x+base+4) = x1;
  float4 r0 = ld4(r+base), r1 = ld4(r+base+4);
  r0.x -= alpha*st.a.x; r0.y -= alpha*st.a.y; r0.z -= alpha*st.a.z; r0.w -= alpha*st.a.w;
  r1.x -= alpha*st.b.x; r1.y -= alpha*st.b.y; r1.z -= alpha*st.b.z; r1.w -= alpha*st.b.w;
  *(float4*)(r+base)   = r0;
  *(float4*)(r+base+4) = r1;
  float rho = r0.x*r0.x + r0.y*r0.y + r0.z*r0.z + r0.w*r0.w
            + r1.x*r1.x + r1.y*r1.y + r1.z*r1.z + r1.w*r1.w;
  block_atomic_sum(rho, scal + RHO_OFF + ((it+1)*B_+bb)*SLOTS_ + slot, lds);
}

__global__ __launch_bounds__(256) void k_b_fin(const float* __restrict__ x,
                                               const float* __restrict__ r,
                                               const float* __restrict__ p,
                                               const float* __restrict__ ref,
                                               float* __restrict__ out,
                                               float* scal, int it)
{
  __shared__ float xs[2048];
  __shared__ float lds[12];
  IDX_SETUP
  float num = read_sum(scal + RHO_OFF + (it*B_+bb)*SLOTS_);
  float den = read_sum(scal + ETA_OFF + (it*B_+bb)*SLOTS_);
  float alpha = num / (den + EPS_);
  F8 c, st;
  stencil1(p, base, w, h, zc, c, st);
  float4 x0 = ld4(x+base), x1 = ld4(x+base+4);
  x0.x += alpha*c.a.x; x0.y += alpha*c.a.y; x0.z += alpha*c.a.z; x0.w += alpha*c.a.w;
  x1.x += alpha*c.b.x; x1.y += alpha*c.b.y; x1.z += alpha*c.b.z; x1.w += alpha*c.b.w;
  float4 r0 = ld4(r+base), r1 = ld4(r+base+4);
  r0.x -= alpha*st.a.x; r0.y -= alpha*st.a.y; r0.z -= alpha*st.a.z; r0.w -= alpha*st.a.w;
  r1.x -= alpha*st.b.x; r1.y -= alpha*st.b.y; r1.z -= alpha*st.b.z; r1.w -= alpha*st.b.w;
  float rho = r0.x*r0.x + r0.y*r0.y + r0.z*r0.z + r0.w*r0.w
            + r1.x*r1.x + r1.y*r1.y + r1.z*r1.z + r1.w*r1.w;
  const int t = threadIdx.x;
  xs[t*8+0] = x0.x; xs[t*8+1] = x0.y; xs[t*8+2] = x0.z; xs[t*8+3] = x0.w;
  xs[t*8+4] = x1.x; xs[t*8+5] = x1.y; xs[t*8+6] = x1.z; xs[t*8+7] = x1.w;
  float4 f0 = ld4(ref+base), f1 = ld4(ref+base+4);
  float d0 = x0.x-f0.x, d1 = x0.y-f0.y, d2 = x0.z-f0.z, d3 = x0.w-f0.w;
  float d4 = x1.x-f1.x, d5 = x1.y-f1.y, d6 = x1.z-f1.z, d7 = x1.w-f1.w;
  float loss = d0*d0+d1*d1+d2*d2+d3*d3+d4*d4+d5*d5+d6*d6+d7*d7;
  float me = fmaxf(fmaxf(fmaxf(fabsf(d0),fabsf(d1)),fmaxf(fabsf(d2),fabsf(d3))),
                   fmaxf(fmaxf(fabsf(d4),fabsf(d5)),fmaxf(fabsf(d6),fabsf(d7))));
  float rs = wsum(rho), ls = wsum(loss), ms = wmaxr(me);
  int wid = t >> 6, lane = t & 63;
  if (lane == 0) { lds[wid] = rs; lds[4+wid] = ls; lds[8+wid] = ms; }
  __syncthreads();
  if (t == 0) {
    atomicAdd(scal + RHO_OFF + ((it+1)*B_+bb)*SLOTS_ + slot, lds[0]+lds[1]+lds[2]+lds[3]);
    atomicAdd(scal + LOSS_OFF + slot, lds[4]+lds[5]+lds[6]+lds[7]);
    float bm = fmaxf(fmaxf(lds[8],lds[9]), fmaxf(lds[10],lds[11]));
    atomicMax((unsigned int*)(scal + MAXE_OFF) + slot, __float_as_uint(bm));
  }
  const int S = flat * 2048;
  #pragma unroll
  for (int c2 = 0; c2 < 2; ++c2) {
    int q = t + 256*c2;
    if (q < 511) {
      float4 v = make_float4(xs[3+4*q], xs[4+4*q], xs[5+4*q], xs[6+4*q]);
      *(float4*)(out + S + 4 + 4*q) = v;
    } else if (q == 511) {
      out[S+1] = xs[0]; out[S+2] = xs[1]; out[S+3] = xs[2];
      out[S+2048] = xs[2047];
    }
  }
}

__global__ __launch_bounds__(64) void k_scal(const float* scal, float* out)
{
  int lane = threadIdx.x;
  float loss = wsum(scal[LOSS_OFF + lane]);
  float me   = wmaxr(__uint_as_float(((const unsigned int*)scal)[MAXE_OFF + lane]));
  float rho_sum = 0.f;
  for (int bb = 0; bb < B_; ++bb)
    rho_sum += wsum(scal[RHO_OFF + (ITER_*B_+bb)*SLOTS_ + lane]);
  if (lane == 0) {
    out[0]      = loss / (float)N_;
    out[1+N_]   = me;
    out[2+N_]   = rho_sum / (float)B_;
  }
}

extern "C" void kernel_launch(void* const* d_in, const int* in_sizes, int n_in,
                              void* d_out, int out_size, void* d_ws, size_t ws_size,
                              hipStream_t stream) {
  float* x         = (float*)d_in[0];
  const float* b   = (const float*)d_in[1];
  const float* ref = (const float*)d_in[2];
  float* out       = (float*)d_out;

  dim3 grid(W_/32, H_, B_), blk(256);

  size_t needH = ((size_t)9*N_ + SCAL_FLOATS) * sizeof(float);
  if (ws_size >= needH) {
    /* ---- history path: no x traffic inside the loop ---- */
    float* r    = (float*)d_ws;
    float* ph   = r + N_;                 /* p_0..p_7, contiguous */
    float* scal = ph + (size_t)8*N_;
    (void)hipMemsetAsync(scal, 0, SCAL_FLOATS*sizeof(float), stream);

    k_init<<<grid, blk, 0, stream>>>(x, b, r, scal);
    k_a0<<<grid, blk, 0, stream>>>(r, ph, scal);
    for (int it = 0; it < ITER_; ++it) {
      if (it < ITER_-1) {
        k_bh<<<grid, blk, 0, stream>>>(r, ph + (size_t)it*N_, scal, it);
        k_a<<<grid, blk, 0, stream>>>(r, ph + (size_t)it*N_, ph + (size_t)(it+1)*N_, scal, it+1);
      } else {
        k_bh_last<<<grid, blk, 0, stream>>>(r, ph + (size_t)it*N_, scal, it);
      }
    }
    k_recon<<<grid, blk, 0, stream>>>(x, ref, ph, out, scal);
    k_scal<<<1, 64, 0, stream>>>(scal, out);
  } else {
    /* ---- fallback: round-3 scheme ---- */
    float* r  = (float*)d_ws;
    float* p0 = r + N_;
    float* p1;
    float* scal;
    size_t need3 = ((size_t)3*N_ + SCAL_FLOATS) * sizeof(float);
    if (ws_size >= need3) { p1 = p0 + N_; scal = p1 + N_; }
    else                  { p1 = (float*)d_out; scal = p0 + N_; }
    (void)hipMemsetAsync(scal, 0, SCAL_FLOATS*sizeof(float), stream);

    k_init<<<grid, blk, 0, stream>>>(x, b, r, scal);
    float* pa = p1;
    float* pb = p0;
    for (int it = 0; it < ITER_; ++it) {
      if (it == 0) k_a0<<<grid, blk, 0, stream>>>(r, pa, scal);
      else         k_a<<<grid, blk, 0, stream>>>(r, pb, pa, scal, it);
      if (it < ITER_-1) k_b<<<grid, blk, 0, stream>>>(x, r, pa, scal, it);
      else              k_b_fin<<<grid, blk, 0, stream>>>(x, r, pa, ref, out, scal, it);
      float* t = pa; pa = pb; pb = t;
    }
    k_scal<<<1, 64, 0, stream>>>(scal, out);
  }
}